// Round 1
// baseline (184.289 us; speedup 1.0000x reference)
//
#include <hip/hip_runtime.h>
#include <hip/hip_bf16.h>
#include <stdint.h>

#define KD 256
#define NPIX 131072
#define NCM 190
#define CMP 192
#define LAMBDA 0.00390625f
#define LN_EPS 1e-5f

typedef __attribute__((ext_vector_type(4))) float f32x4;
typedef __attribute__((ext_vector_type(8))) short bf16x8;

__device__ __forceinline__ float wred(float v) {
#pragma unroll
  for (int off = 32; off > 0; off >>= 1) v += __shfl_xor(v, off, 64);
  return v;
}

// round-to-nearest-even f32 -> bf16 bits
__device__ __forceinline__ ushort f2bf(float f) {
  uint32_t u = __float_as_uint(f);
  u += 0x7FFFu + ((u >> 16) & 1u);
  return (ushort)(u >> 16);
}

// ---------------- kernel 1: prototype-side prep (tiny) ----------------
// Builds B' [192][512] bf16:  cols 0..255  = 2 * pbar[cm][k]
//                              cols 256..511 = (2/K) * sqrt(proto_var[cm][k])
// and spc[cm] = 2 + (1/K) * sum_k proto_var[cm][k]
__global__ __launch_bounds__(256) void proto_prep_kernel(
    const float* __restrict__ protos, const float* __restrict__ pvar,
    const float* __restrict__ gam, const float* __restrict__ bet,
    const float* __restrict__ eps_p,
    ushort* __restrict__ Bp, float* __restrict__ spc) {
  const int wave = threadIdx.x >> 6;
  const int lane = threadIdx.x & 63;
  const int cm = blockIdx.x * 4 + wave;
  if (cm >= CMP) return;
  ushort* row = Bp + (size_t)cm * 512;
  if (cm >= NCM) {  // zero pad rows 190,191
    for (int j = lane; j < 512; j += 64) row[j] = 0;
    if (lane == 0) spc[cm] = 0.f;
    return;
  }
  const int k0 = lane * 4;
  f32x4 pv = *(const f32x4*)(pvar + (size_t)cm * KD + k0);
  f32x4 pm = *(const f32x4*)(protos + (size_t)cm * KD + k0);
  f32x4 gg = *(const f32x4*)(gam + k0);
  f32x4 bb = *(const f32x4*)(bet + k0);
  float spv = wred(pv.x + pv.y + pv.z + pv.w);
  f32x4 acc = {0.f, 0.f, 0.f, 0.f};
#pragma unroll
  for (int r = 0; r < 2; ++r) {
    f32x4 e = *(const f32x4*)(eps_p + ((size_t)r * NCM + cm) * KD + k0);
    f32x4 v;
    v.x = e.x * pv.x + pm.x;
    v.y = e.y * pv.y + pm.y;
    v.z = e.z * pv.z + pm.z;
    v.w = e.w * pv.w + pm.w;
    float s1 = wred(v.x + v.y + v.z + v.w);
    float s2 = wred(v.x * v.x + v.y * v.y + v.z * v.z + v.w * v.w);
    float mean = s1 * (1.f / KD);
    float var = s2 * (1.f / KD) - mean * mean;
    float rs = rsqrtf(var + LN_EPS);
    f32x4 y;
    y.x = (v.x - mean) * rs * gg.x + bb.x;
    y.y = (v.y - mean) * rs * gg.y + bb.y;
    y.z = (v.z - mean) * rs * gg.z + bb.z;
    y.w = (v.w - mean) * rs * gg.w + bb.w;
    float n2 = wred(y.x * y.x + y.y * y.y + y.z * y.z + y.w * y.w);
    float inv = 1.f / fmaxf(sqrtf(n2), 1e-12f);
    acc.x += y.x * inv;
    acc.y += y.y * inv;
    acc.z += y.z * inv;
    acc.w += y.w * inv;
  }
  // 2 * pbar = 2 * (acc/2) = acc
  row[k0 + 0] = f2bf(acc.x);
  row[k0 + 1] = f2bf(acc.y);
  row[k0 + 2] = f2bf(acc.z);
  row[k0 + 3] = f2bf(acc.w);
  const float s = 2.f * LAMBDA;
  row[256 + k0 + 0] = f2bf(s * sqrtf(pv.x));
  row[256 + k0 + 1] = f2bf(s * sqrtf(pv.y));
  row[256 + k0 + 2] = f2bf(s * sqrtf(pv.z));
  row[256 + k0 + 3] = f2bf(s * sqrtf(pv.w));
  if (lane == 0) spc[cm] = 2.f + LAMBDA * spv;
}

// ---------------- kernel 2: fused pixel prep + GEMM + epilogue ----------------
// block = 256 thr (4 waves), 64 pixel rows/block.
// Phase A: wave w preprocesses rows 16w..16w+15 into swizzled LDS A [64][512] bf16
//          (first 256 = xbar, last 256 = sqrt(x_var)); sxl[m] = lambda*sum(x_var).
// Phase B: 16x16x32 bf16 MFMA, A[64][512] x B'[512][192]; wave w owns cols 48w..48w+47.
// out[n*190+col] = acc - spc[col] - sxl[m]
__global__ __launch_bounds__(256, 2) void fused_main_kernel(
    const float* __restrict__ x, const float* __restrict__ xvar,
    const float* __restrict__ gam, const float* __restrict__ bet,
    const float* __restrict__ eps_x,
    const ushort* __restrict__ Bp, const float* __restrict__ spc,
    float* __restrict__ out) {
  __shared__ ushort As[64 * 512];
  __shared__ float sxl[64];
  const int tid = threadIdx.x;
  const int wave = tid >> 6;
  const int lane = tid & 63;
  const int64_t nbase = (int64_t)blockIdx.x * 64;
  const int k0 = lane * 4;
  const f32x4 gg = *(const f32x4*)(gam + k0);
  const f32x4 bb = *(const f32x4*)(bet + k0);

  for (int rr = 0; rr < 16; ++rr) {
    const int m = wave * 16 + rr;
    const int64_t n = nbase + m;
    f32x4 xv = *(const f32x4*)(xvar + n * KD + k0);
    f32x4 xm = *(const f32x4*)(x + n * KD + k0);
    float sxv = wred(xv.x + xv.y + xv.z + xv.w);
    f32x4 acc = {0.f, 0.f, 0.f, 0.f};
#pragma unroll
    for (int r = 0; r < 2; ++r) {
      f32x4 e = *(const f32x4*)(eps_x + ((int64_t)r * NPIX + n) * KD + k0);
      f32x4 v;
      v.x = e.x * xv.x + xm.x;
      v.y = e.y * xv.y + xm.y;
      v.z = e.z * xv.z + xm.z;
      v.w = e.w * xv.w + xm.w;
      float s1 = wred(v.x + v.y + v.z + v.w);
      float s2 = wred(v.x * v.x + v.y * v.y + v.z * v.z + v.w * v.w);
      float mean = s1 * (1.f / KD);
      float var = s2 * (1.f / KD) - mean * mean;
      float rs = rsqrtf(var + LN_EPS);
      f32x4 y;
      y.x = (v.x - mean) * rs * gg.x + bb.x;
      y.y = (v.y - mean) * rs * gg.y + bb.y;
      y.z = (v.z - mean) * rs * gg.z + bb.z;
      y.w = (v.w - mean) * rs * gg.w + bb.w;
      float n2 = wred(y.x * y.x + y.y * y.y + y.z * y.z + y.w * y.w);
      float inv = 1.f / fmaxf(sqrtf(n2), 1e-12f);
      acc.x += y.x * inv;
      acc.y += y.y * inv;
      acc.z += y.z * inv;
      acc.w += y.w * inv;
    }
    union {
      uint2 u;
      ushort s[4];
    } w0, w1;
    w0.s[0] = f2bf(0.5f * acc.x);
    w0.s[1] = f2bf(0.5f * acc.y);
    w0.s[2] = f2bf(0.5f * acc.z);
    w0.s[3] = f2bf(0.5f * acc.w);
    w1.s[0] = f2bf(sqrtf(xv.x));
    w1.s[1] = f2bf(sqrtf(xv.y));
    w1.s[2] = f2bf(sqrtf(xv.z));
    w1.s[3] = f2bf(sqrtf(xv.w));
    char* rowp = (char*)As + m * 1024;
    const int sw = (m & 7) << 4;  // XOR swizzle: 16B chunks spread across banks
    *(uint2*)(rowp + ((8 * lane) ^ sw)) = w0.u;
    *(uint2*)(rowp + ((512 + 8 * lane) ^ sw)) = w1.u;
    if (lane == 0) sxl[m] = LAMBDA * sxv;
  }
  __syncthreads();

  f32x4 acc[4][3];
#pragma unroll
  for (int s = 0; s < 4; ++s)
#pragma unroll
    for (int t = 0; t < 3; ++t) acc[s][t] = (f32x4){0.f, 0.f, 0.f, 0.f};

  const int colq = lane & 15;
  const int kq = lane >> 4;
  const int colbase = wave * 48;
#pragma unroll
  for (int kk = 0; kk < 16; ++kk) {
    const int kbyte = kk * 64 + kq * 16;
    bf16x8 af[4];
#pragma unroll
    for (int s = 0; s < 4; ++s) {
      const int m = s * 16 + colq;
      af[s] = *(const bf16x8*)((const char*)As + m * 1024 + (kbyte ^ ((m & 7) << 4)));
    }
#pragma unroll
    for (int t = 0; t < 3; ++t) {
      const int cmc = colbase + t * 16 + colq;
      bf16x8 bfr = *(const bf16x8*)((const char*)Bp + (size_t)cmc * 1024 + kbyte);
#pragma unroll
      for (int s = 0; s < 4; ++s)
        acc[s][t] = __builtin_amdgcn_mfma_f32_16x16x32_bf16(af[s], bfr, acc[s][t], 0, 0, 0);
    }
  }

#pragma unroll
  for (int t = 0; t < 3; ++t) {
    const int col = colbase + t * 16 + colq;
    if (col < NCM) {
      const float sc = spc[col];
#pragma unroll
      for (int s = 0; s < 4; ++s) {
#pragma unroll
        for (int j = 0; j < 4; ++j) {
          const int m = s * 16 + kq * 4 + j;
          out[(nbase + m) * NCM + col] = acc[s][t][j] - sc - sxl[m];
        }
      }
    }
  }
}

extern "C" void kernel_launch(void* const* d_in, const int* in_sizes, int n_in,
                              void* d_out, int out_size, void* d_ws, size_t ws_size,
                              hipStream_t stream) {
  const float* x = (const float*)d_in[0];
  const float* x_var = (const float*)d_in[1];
  const float* protos = (const float*)d_in[2];
  const float* pvar = (const float*)d_in[3];
  const float* gam = (const float*)d_in[4];
  const float* bet = (const float*)d_in[5];
  const float* eps_x = (const float*)d_in[6];
  const float* eps_p = (const float*)d_in[7];
  float* out = (float*)d_out;

  ushort* Bp = (ushort*)d_ws;                        // 192*512*2 = 196608 B
  float* spc = (float*)((char*)d_ws + CMP * 512 * 2);  // 192*4 B

  proto_prep_kernel<<<CMP / 4, 256, 0, stream>>>(protos, pvar, gam, bet, eps_p, Bp, spc);
  fused_main_kernel<<<NPIX / 64, 256, 0, stream>>>(x, x_var, gam, bet, eps_x, Bp, spc, out);
}